// Round 16
// baseline (43.186 us; speedup 1.0000x reference)
//
#include <hip/hip_runtime.h>
#include <math.h>

#define NB   16
#define NQ   4096
#define NTGT 128
#define CELEMS (NB * NQ * NTGT)

#define NSLOT 64           // rowmin slots per batch
#define AT   256           // lsa/fused block size (4 waves)
#define ACPT 16            // cols per lsa thread (NQ / AT)
#define NCOST 1024         // C-writer blocks (2048 float4 each)

typedef unsigned long long u64;

// ---------------- kernel 1: per-row (target) min/argmin only -----------------
__global__ __launch_bounds__(256) void rowmin_kernel(
    const float* __restrict__ outputs,
    const float* __restrict__ targets,
    u64*   __restrict__ rowkey2)      // [NB][NSLOT][NTGT]
{
    __shared__ u64 part[4][NTGT];     // 4 KB
    const int tid  = threadIdx.x;
    const int t4   = tid & 31;
    const int b    = blockIdx.x >> 6;            // 64 blocks per batch
    const int blk  = blockIdx.x & (NSLOT - 1);
    const int idx0 = blockIdx.x * 2048 + tid;

    const float4* tg = reinterpret_cast<const float4*>(targets) + (b << 7) + (t4 << 2);
    float4 g[4];
    #pragma unroll
    for (int f = 0; f < 4; ++f) g[f] = tg[f];

    u64 keymin[4] = {~0ull, ~0ull, ~0ull, ~0ull};

    #pragma unroll
    for (int e = 0; e < 8; ++e) {
        int idx = idx0 + 256 * e;
        int bq  = idx >> 5;
        float4 o = reinterpret_cast<const float4*>(outputs)[bq];
        u64 q = (u64)(unsigned)(bq & (NQ - 1));
        #pragma unroll
        for (int f = 0; f < 4; ++f) {
            float4 gg = g[f];
            float r = (fabsf(o.x - gg.x) + fabsf(o.y - gg.y)) +
                      (fabsf(o.z - gg.z) + fabsf(o.w - gg.w));
            u64 key = (((u64)__float_as_uint(r)) << 32) | q;
            if (key < keymin[f]) keymin[f] = key;
        }
    }

    #pragma unroll
    for (int f = 0; f < 4; ++f) {
        u64 ov = __shfl_xor(keymin[f], 32);
        if (ov < keymin[f]) keymin[f] = ov;
    }
    if ((tid & 63) < 32) {
        int w = tid >> 6;
        #pragma unroll
        for (int f = 0; f < 4; ++f) part[w][(t4 << 2) + f] = keymin[f];
    }
    __syncthreads();

    if (tid < NTGT) {
        u64 k = part[0][tid];
        #pragma unroll
        for (int s = 1; s < 4; ++s) { u64 ov = part[s][tid]; if (ov < k) k = ov; }
        rowkey2[(((size_t)b * NSLOT) + blk) * NTGT + tid] = k;
    }
}

// ---------------- kernel 2: fused {lsa blocks 0..15} + {C-writer blocks} -----
// lsa: exact f64 Jonker-Volgenant (row-reduction duals + greedy tight-edge
// claim + shortest-augmenting-path) -> provably optimal matching == scipy
// (unique optimum; all arithmetic exact: multiples of 2^-24 << 2^53).
// Per-thread 16-column state (outputs/shortest/v/row4col-copy) in NAMED
// registers. Argmin reduce: packed u64 key (cand f64 bits, low 20 bits
// replaced by (row4col+1)<<12 | col; rigorous bound cand<128 -> low 21
// mantissa bits zero -> lossless) via per-wave shfl + single LDS atomicMin
// (3-slot rotation). One barrier per Dijkstra iteration.
__global__ __launch_bounds__(AT, 1) void fused_kernel(
    const float* __restrict__ outputs,
    const float* __restrict__ targets,
    const u64*   __restrict__ rowkey2,
    float* __restrict__ C,
    float* __restrict__ row_out,   // [NB, NTGT] as float
    float* __restrict__ col_out)   // [NB, NTGT] as float
{
    __shared__ unsigned claim_[NQ];         // 16 KB
    __shared__ short  row4col_[NQ];         // 8 KB
    __shared__ unsigned char path_[NQ];     // 4 KB
    __shared__ unsigned char vtouch_[NQ];   // 4 KB
    __shared__ float4 tgt_[NTGT];           // 2 KB
    __shared__ double u_[NTGT];             // 1 KB
    __shared__ u64    red2_[2][NTGT];       // 2 KB
    __shared__ int    rowarg_[NTGT];
    __shared__ short  col4row_[NTGT];
    __shared__ short  left_[NTGT];
    __shared__ short  sc_i[NTGT];
    __shared__ double sc_v[NTGT];
    __shared__ u64    redk_[3];
    __shared__ u64    bmask_[2];

    const int tid = threadIdx.x;

    if (blockIdx.x >= NB) {
        // ---------------- C-writer role: pure streaming ----------------
        const int blk = blockIdx.x - NB;
        const int t4  = tid & 31;
        const float4* tg = reinterpret_cast<const float4*>(targets);
        float4 g0, g1, g2, g3;
        {
            int b = (blk * 2048 + tid) >> 17;
            const float4* tgb = tg + (b << 7) + (t4 << 2);
            g0 = tgb[0]; g1 = tgb[1]; g2 = tgb[2]; g3 = tgb[3];
        }
        #pragma unroll
        for (int e = 0; e < 8; ++e) {
            int f  = blk * 2048 + e * 256 + tid;   // float4 index into C
            int bq = f >> 5;
            float4 o = reinterpret_cast<const float4*>(outputs)[bq];
            float4 r;
            r.x = (fabsf(o.x - g0.x) + fabsf(o.y - g0.y)) + (fabsf(o.z - g0.z) + fabsf(o.w - g0.w));
            r.y = (fabsf(o.x - g1.x) + fabsf(o.y - g1.y)) + (fabsf(o.z - g1.z) + fabsf(o.w - g1.w));
            r.z = (fabsf(o.x - g2.x) + fabsf(o.y - g2.y)) + (fabsf(o.z - g2.z) + fabsf(o.w - g2.w));
            r.w = (fabsf(o.x - g3.x) + fabsf(o.y - g3.y)) + (fabsf(o.z - g3.z) + fabsf(o.w - g3.w));
            reinterpret_cast<float4*>(C)[f] = r;
        }
        return;
    }

    // ---------------- lsa role: one block per batch ----------------
    const int b = blockIdx.x;
    const float4* outq = reinterpret_cast<const float4*>(outputs) + b * NQ;

#define FORALL(M) \
    M(0,oo0,sh0,vv0,rc0)   M(1,oo1,sh1,vv1,rc1)   M(2,oo2,sh2,vv2,rc2)   M(3,oo3,sh3,vv3,rc3) \
    M(4,oo4,sh4,vv4,rc4)   M(5,oo5,sh5,vv5,rc5)   M(6,oo6,sh6,vv6,rc6)   M(7,oo7,sh7,vv7,rc7) \
    M(8,oo8,sh8,vv8,rc8)   M(9,oo9,sh9,vv9,rc9)   M(10,oo10,sh10,vv10,rc10) M(11,oo11,sh11,vv11,rc11) \
    M(12,oo12,sh12,vv12,rc12) M(13,oo13,sh13,vv13,rc13) M(14,oo14,sh14,vv14,rc14) M(15,oo15,sh15,vv15,rc15)

    // named per-column registers
#define DECL(n, on, shn, vvn, rcn) \
    float4 on = outq[tid + AT * n]; double shn = 0.0, vvn = 0.0; int rcn = -1;
    FORALL(DECL)
#undef DECL

    #pragma unroll
    for (int kk = 0; kk < ACPT; ++kk) {
        int k = tid + AT * kk;
        row4col_[k] = -1;
        claim_[k] = 0xFFFFFFFFu;
        vtouch_[k] = 0;
    }
    if (tid == 0) { redk_[0] = ~0ull; redk_[1] = ~0ull; redk_[2] = ~0ull; }

    // reduce the 64 rowkey slots per row (coalesced)
    {
        const int t = tid & 127, s = tid >> 7;            // 2 slices x 32 slots
        const u64* rk = rowkey2 + (size_t)b * NSLOT * NTGT;
        u64 k = ~0ull;
        #pragma unroll
        for (int gg = 0; gg < NSLOT / 2; ++gg) {
            u64 ov = rk[(s * (NSLOT / 2) + gg) * NTGT + t];
            if (ov < k) k = ov;
        }
        red2_[s][t] = k;
    }
    __syncthreads();

    if (tid < NTGT) {
        u64 key = red2_[0][tid];
        u64 ov  = red2_[1][tid]; if (ov < key) key = ov;
        u_[tid] = (double)__uint_as_float((unsigned)(key >> 32));
        rowarg_[tid] = (int)(key & 0xffffffffu);
        tgt_[tid] = reinterpret_cast<const float4*>(targets)[b * NTGT + tid];
    }
    __syncthreads();

    // greedy claim of tight edges: lowest row wins each contested column
    if (tid < NTGT) atomicMin(&claim_[rowarg_[tid]], (unsigned)tid);
    __syncthreads();

    bool un = false;
    if (tid < NTGT) {
        int j = rowarg_[tid];
        bool won = (claim_[j] == (unsigned)tid);
        col4row_[tid] = won ? (short)j : (short)-1;
        if (won) row4col_[j] = (short)tid;
        un = !won;
    }
    {
        u64 m = __ballot(un);
        if ((tid & 63) == 0 && (tid >> 6) < 2) bmask_[tid >> 6] = m;
    }
    __syncthreads();
    const int nleft = __popcll(bmask_[0]) + __popcll(bmask_[1]);
    if (un) {
        int lane = tid & 63, w = tid >> 6;
        int r = __popcll(bmask_[w] & ((1ull << lane) - 1)) + (w ? __popcll(bmask_[0]) : 0);
        left_[r] = (short)tid;
    }
    __syncthreads();

    // initial row4col register copies
#define RELOAD(n, on, shn, vvn, rcn) rcn = row4col_[tid + AT * n];
    FORALL(RELOAD)

    unsigned s3 = 0;   // rotating reduce slot

#define COSTN(g, on) ((fabsf((on).x - (g).x) + fabsf((on).y - (g).y)) + \
                      (fabsf((on).z - (g).z) + fabsf((on).w - (g).w)))

    for (int li = 0; li < nleft; ++li) {
        const int cur = left_[li];
        const int j0  = rowarg_[cur];
        const bool fast = (vtouch_[j0] == 0);
        int      i;
        double   minv = 0.0;
        int      fj   = -1;
        int      Lns  = 0;
        unsigned rem  = 0xFFFFu;
        unsigned pend = 0u;
        bool     first = true;

        const double uc = u_[cur];
        const float4 gc = tgt_[cur];

        if (fast) {
            // analytic iteration-1: pick j0 (cand=0 is the unique global min)
            i = row4col_[j0];
            fj = j0; Lns = 1;
            const bool mine = ((j0 & (AT - 1)) == tid);
            const int  slot = j0 >> 8;
            if (mine) {
                rem  &= ~(1u << slot);
                pend |=  (1u << slot);
                path_[j0] = (unsigned char)cur;
                #define SETJ0(n, on, shn, vvn, rcn) if (slot == n) shn = 0.0;
                FORALL(SETJ0)
                #undef SETJ0
            }
            if (tid == 0) { sc_i[0] = (short)i; sc_v[0] = 0.0; }
        } else {
            i = cur;
        }

        while (true) {
            if (tid == 0) redk_[s3 == 2 ? 0 : s3 + 1] = ~0ull;   // reset NEXT slot
            const double ui = u_[i];
            const float4 g  = tgt_[i];

            double bv = (double)INFINITY;
            int    bn = 0;

            if (first && fast) {
                // fused iterations 1+2: s = min(cand_cur, cand_win);
                // path = winner only on strict <
                #define FSTEP(n, on, shn, vvn, rcn)                             \
                {   double cand_c = ((0.0 + (double)COSTN(gc, on)) - uc) - vvn; \
                    double cand_w = ((0.0 + (double)COSTN(g,  on)) - ui) - vvn; \
                    bool wless = cand_w < cand_c;                               \
                    double s = wless ? cand_w : cand_c;                         \
                    if ((rem >> n) & 1u) {                                      \
                        shn = s;                                                \
                        path_[tid + AT * n] = (unsigned char)(wless ? i : cur); \
                        if (s < bv) { bv = s; bn = n; }                         \
                    }                                                           \
                }
                FORALL(FSTEP)
                #undef FSTEP
            } else if (first) {
                // plain reference iteration-1 scan from cur
                #define ISTEP(n, on, shn, vvn, rcn)                             \
                {   double s = ((0.0 + (double)COSTN(gc, on)) - uc) - vvn;      \
                    shn = s;                                                    \
                    path_[tid + AT * n] = (unsigned char)cur;                   \
                    if (s < bv) { bv = s; bn = n; }                             \
                }
                FORALL(ISTEP)
                #undef ISTEP
            } else {
                // min-update scan from row i — pure register arithmetic
                #define USTEP(n, on, shn, vvn, rcn)                             \
                {   double cand = ((minv + (double)COSTN(g, on)) - ui) - vvn;   \
                    bool valid = (rem >> n) & 1u;                               \
                    if (valid && cand < shn) {                                  \
                        shn = cand;                                             \
                        path_[tid + AT * n] = (unsigned char)i;                 \
                    }                                                           \
                    if (valid && shn < bv) { bv = shn; bn = n; }                \
                }
                FORALL(USTEP)
                #undef USTEP
            }
            first = false;

            // packed key: cand f64 bits (low 20 zero) | (row4col+1)<<12 | col
            int bi = tid + (bn << 8);
            int brc = -1;
            #define SELR(n, on, shn, vvn, rcn) if (bn == n) brc = rcn;
            FORALL(SELR)
            #undef SELR
            u64 key = (__double_as_longlong(bv) & ~0xFFFFFull)
                    | ((u64)(unsigned)(brc + 1) << 12) | (unsigned)bi;
            #pragma unroll
            for (int off = 32; off > 0; off >>= 1) {
                u64 ok = __shfl_down(key, off);
                if (ok < key) key = ok;
            }
            if ((tid & 63) == 0) atomicMin(&redk_[s3], key);
            __syncthreads();

            u64 fkey = redk_[s3];
            s3 = (s3 == 2) ? 0 : s3 + 1;

            fj   = (int)(fkey & 0xFFFull);
            int r = (int)((fkey >> 12) & 0xFFull) - 1;
            minv = __longlong_as_double((long long)(fkey & ~0xFFFFFull));  // exact

            if ((fj & (AT - 1)) == tid) {
                rem &= ~(1u << (fj >> 8));
                if (r >= 0) pend |= (1u << (fj >> 8));
            }
            if (r < 0) break;                 // sink found
            if (tid == 0) { sc_i[Lns] = (short)r; sc_v[Lns] = minv; }
            Lns++;
            i = r;
        }

        // ---- row end: duals + augment ----
        const double dfin = minv;
        // owner v-patch in registers (sink term exactly 0, excluded from pend)
        #define VPAT(n, on, shn, vvn, rcn)                                      \
        if (pend & (1u << n)) {                                                 \
            vvn -= dfin - shn;                                                  \
            vtouch_[tid + AT * n] = 1;                                          \
        }
        FORALL(VPAT)
        #undef VPAT
        if (tid == 0) {
            u_[cur] += dfin;
            for (int e = 0; e < Lns; ++e)
                u_[sc_i[e]] += dfin - sc_v[e];   // pre-augment matched row of pick e
            int j = fj;
            while (true) {
                int i2 = path_[j];
                row4col_[j] = (short)i2;
                int nj = col4row_[i2];
                col4row_[i2] = (short)j;
                j = nj;
                if (i2 == cur) break;
            }
        }
        __syncthreads();   // publish row4col_/col4row_/u_ before next row
        FORALL(RELOAD)     // refresh row4col register copies
    }
#undef RELOAD
#undef COSTN
#undef FORALL

    // outputs (transposed case): order = argsort(col4row);
    // row_ind = col4row[order]; col_ind = order.
    if (tid < NTGT) {
        int val = col4row_[tid];
        int rank = 0;
        #pragma unroll
        for (int k = 0; k < NTGT; ++k) rank += (col4row_[k] < val);
        row_out[b * NTGT + rank] = (float)val;
        col_out[b * NTGT + rank] = (float)tid;
    }
}

extern "C" void kernel_launch(void* const* d_in, const int* in_sizes, int n_in,
                              void* d_out, int out_size, void* d_ws, size_t ws_size,
                              hipStream_t stream) {
    const float* outputs = (const float*)d_in[0];   // [16, 4096, 4]
    const float* targets = (const float*)d_in[1];   // [16, 128, 4]
    float* out = (float*)d_out;                     // C | row_ind | col_ind (as f32)

    u64* rowkey2 = (u64*)d_ws;                      // NB*NSLOT*NTGT*8 = 1 MB

    hipLaunchKernelGGL(rowmin_kernel, dim3(NB * NSLOT), dim3(256), 0, stream,
                       outputs, targets, rowkey2);
    hipLaunchKernelGGL(fused_kernel, dim3(NB + NCOST), dim3(AT), 0, stream,
                       outputs, targets, rowkey2, out,
                       out + CELEMS, out + CELEMS + NB * NTGT);
}

// Round 17
// 31.731 us; speedup vs baseline: 1.3610x; 1.3610x over previous
//
#include <hip/hip_runtime.h>
#include <math.h>

#define NB   16
#define NQ   4096
#define NTGT 128
#define CELEMS (NB * NQ * NTGT)

#define NSLOT 64           // rowmin slots per batch
#define AT   512           // block size (both roles) — 8 waves for latency hiding
#define ACPT 8             // cols per lsa thread (NQ / AT)
#define ANW  (AT / 64)     // 8 waves
#define NCOST (CELEMS / 4 / 2048)   // 1024 C-writer blocks (4 float4/thread)

typedef unsigned long long u64;

// ---------------- kernel 1: per-row (target) min/argmin only -----------------
__global__ __launch_bounds__(256) void rowmin_kernel(
    const float* __restrict__ outputs,
    const float* __restrict__ targets,
    u64*   __restrict__ rowkey2)      // [NB][NSLOT][NTGT]
{
    __shared__ u64 part[4][NTGT];     // 4 KB
    const int tid  = threadIdx.x;
    const int t4   = tid & 31;
    const int b    = blockIdx.x >> 6;            // 64 blocks per batch
    const int blk  = blockIdx.x & (NSLOT - 1);
    const int idx0 = blockIdx.x * 2048 + tid;

    const float4* tg = reinterpret_cast<const float4*>(targets) + (b << 7) + (t4 << 2);
    float4 g[4];
    #pragma unroll
    for (int f = 0; f < 4; ++f) g[f] = tg[f];

    u64 keymin[4] = {~0ull, ~0ull, ~0ull, ~0ull};

    #pragma unroll
    for (int e = 0; e < 8; ++e) {
        int idx = idx0 + 256 * e;
        int bq  = idx >> 5;
        float4 o = reinterpret_cast<const float4*>(outputs)[bq];
        u64 q = (u64)(unsigned)(bq & (NQ - 1));
        #pragma unroll
        for (int f = 0; f < 4; ++f) {
            float4 gg = g[f];
            float r = (fabsf(o.x - gg.x) + fabsf(o.y - gg.y)) +
                      (fabsf(o.z - gg.z) + fabsf(o.w - gg.w));
            u64 key = (((u64)__float_as_uint(r)) << 32) | q;
            if (key < keymin[f]) keymin[f] = key;
        }
    }

    #pragma unroll
    for (int f = 0; f < 4; ++f) {
        u64 ov = __shfl_xor(keymin[f], 32);
        if (ov < keymin[f]) keymin[f] = ov;
    }
    if ((tid & 63) < 32) {
        int w = tid >> 6;
        #pragma unroll
        for (int f = 0; f < 4; ++f) part[w][(t4 << 2) + f] = keymin[f];
    }
    __syncthreads();

    if (tid < NTGT) {
        u64 k = part[0][tid];
        #pragma unroll
        for (int s = 1; s < 4; ++s) { u64 ov = part[s][tid]; if (ov < k) k = ov; }
        rowkey2[(((size_t)b * NSLOT) + blk) * NTGT + tid] = k;
    }
}

// ---------------- kernel 2: fused {lsa blocks 0..15} + {C-writer blocks} -----
// lsa: exact f64 Jonker-Volgenant -> provably optimal matching == scipy
// (unique optimum; all arithmetic exact: multiples of 2^-24 << 2^53).
// Per-thread 8-column state in NAMED registers. Argmin reduce: packed u64 key
// (cand f64 bits; bound cand<128 -> low 21 mantissa bits zero; low 20 bits
// carry (row4col+1)<<12 | col, preserving exact value + lowest-index ties)
// via per-wave shfl + single LDS atomicMin slot (3-slot rotation).
// One barrier per Dijkstra iteration.
__global__ __launch_bounds__(AT, 1) void fused_kernel(
    const float* __restrict__ outputs,
    const float* __restrict__ targets,
    const u64*   __restrict__ rowkey2,
    float* __restrict__ C,
    float* __restrict__ row_out,   // [NB, NTGT] as float
    float* __restrict__ col_out)   // [NB, NTGT] as float
{
    __shared__ unsigned claim_[NQ];         // 16 KB
    __shared__ short  row4col_[NQ];         // 8 KB
    __shared__ unsigned char path_[NQ];     // 4 KB
    __shared__ unsigned char vtouch_[NQ];   // 4 KB
    __shared__ float4 tgt_[NTGT];           // 2 KB
    __shared__ double u_[NTGT];             // 1 KB
    __shared__ u64    red2_[4][NTGT];       // 4 KB
    __shared__ int    rowarg_[NTGT];
    __shared__ short  col4row_[NTGT];
    __shared__ short  left_[NTGT];
    __shared__ short  sc_i[NTGT];
    __shared__ double sc_v[NTGT];
    __shared__ u64    redk_[3];
    __shared__ u64    bmask_[2];

    const int tid = threadIdx.x;

    if (blockIdx.x >= NB) {
        // ---------------- C-writer role: pure streaming ----------------
        const int blk = blockIdx.x - NB;
        const int t4  = tid & 31;
        const float4* tg = reinterpret_cast<const float4*>(targets);
        float4 g0, g1, g2, g3;
        {
            int b = (blk * 2048 + tid) >> 17;
            const float4* tgb = tg + (b << 7) + (t4 << 2);
            g0 = tgb[0]; g1 = tgb[1]; g2 = tgb[2]; g3 = tgb[3];
        }
        #pragma unroll
        for (int e = 0; e < 4; ++e) {
            int f  = blk * 2048 + e * 512 + tid;   // float4 index into C
            int bq = f >> 5;
            float4 o = reinterpret_cast<const float4*>(outputs)[bq];
            float4 r;
            r.x = (fabsf(o.x - g0.x) + fabsf(o.y - g0.y)) + (fabsf(o.z - g0.z) + fabsf(o.w - g0.w));
            r.y = (fabsf(o.x - g1.x) + fabsf(o.y - g1.y)) + (fabsf(o.z - g1.z) + fabsf(o.w - g1.w));
            r.z = (fabsf(o.x - g2.x) + fabsf(o.y - g2.y)) + (fabsf(o.z - g2.z) + fabsf(o.w - g2.w));
            r.w = (fabsf(o.x - g3.x) + fabsf(o.y - g3.y)) + (fabsf(o.z - g3.z) + fabsf(o.w - g3.w));
            reinterpret_cast<float4*>(C)[f] = r;
        }
        return;
    }

    // ---------------- lsa role: one block per batch ----------------
    const int b = blockIdx.x;
    const float4* outq = reinterpret_cast<const float4*>(outputs) + b * NQ;

#define FORALL(M) \
    M(0,oo0,sh0,vv0,rc0) M(1,oo1,sh1,vv1,rc1) M(2,oo2,sh2,vv2,rc2) M(3,oo3,sh3,vv3,rc3) \
    M(4,oo4,sh4,vv4,rc4) M(5,oo5,sh5,vv5,rc5) M(6,oo6,sh6,vv6,rc6) M(7,oo7,sh7,vv7,rc7)

    // named per-column registers (static indexing only)
#define DECL(n, on, shn, vvn, rcn) \
    float4 on = outq[tid + AT * n]; double shn = 0.0, vvn = 0.0; int rcn = -1;
    FORALL(DECL)
#undef DECL

    #pragma unroll
    for (int kk = 0; kk < ACPT; ++kk) {
        int k = tid + AT * kk;
        row4col_[k] = -1;
        claim_[k] = 0xFFFFFFFFu;
        vtouch_[k] = 0;
    }
    if (tid == 0) { redk_[0] = ~0ull; redk_[1] = ~0ull; redk_[2] = ~0ull; }

    // reduce the 64 rowkey slots per row (coalesced)
    {
        const int t = tid & 127, s = tid >> 7;            // 4 slices x 16 slots
        const u64* rk = rowkey2 + (size_t)b * NSLOT * NTGT;
        u64 k = ~0ull;
        #pragma unroll
        for (int gg = 0; gg < NSLOT / 4; ++gg) {
            u64 ov = rk[(s * (NSLOT / 4) + gg) * NTGT + t];
            if (ov < k) k = ov;
        }
        red2_[s][t] = k;
    }
    __syncthreads();

    if (tid < NTGT) {
        u64 key = red2_[0][tid];
        #pragma unroll
        for (int s = 1; s < 4; ++s) { u64 ov = red2_[s][tid]; if (ov < key) key = ov; }
        u_[tid] = (double)__uint_as_float((unsigned)(key >> 32));
        rowarg_[tid] = (int)(key & 0xffffffffu);
        tgt_[tid] = reinterpret_cast<const float4*>(targets)[b * NTGT + tid];
    }
    __syncthreads();

    // greedy claim of tight edges: lowest row wins each contested column
    if (tid < NTGT) atomicMin(&claim_[rowarg_[tid]], (unsigned)tid);
    __syncthreads();

    bool un = false;
    if (tid < NTGT) {
        int j = rowarg_[tid];
        bool won = (claim_[j] == (unsigned)tid);
        col4row_[tid] = won ? (short)j : (short)-1;
        if (won) row4col_[j] = (short)tid;
        un = !won;
    }
    {
        u64 m = __ballot(un);
        if ((tid & 63) == 0 && (tid >> 6) < 2) bmask_[tid >> 6] = m;
    }
    __syncthreads();
    const int nleft = __popcll(bmask_[0]) + __popcll(bmask_[1]);
    if (un) {
        int lane = tid & 63, w = tid >> 6;
        int r = __popcll(bmask_[w] & ((1ull << lane) - 1)) + (w ? __popcll(bmask_[0]) : 0);
        left_[r] = (short)tid;
    }
    __syncthreads();

    // initial row4col register copies
#define RELOAD(n, on, shn, vvn, rcn) rcn = row4col_[tid + AT * n];
    FORALL(RELOAD)

    unsigned s3 = 0;   // rotating reduce slot

#define COSTN(g, on) ((fabsf((on).x - (g).x) + fabsf((on).y - (g).y)) + \
                      (fabsf((on).z - (g).z) + fabsf((on).w - (g).w)))

    for (int li = 0; li < nleft; ++li) {
        const int cur = left_[li];
        const int j0  = rowarg_[cur];
        const bool fast = (vtouch_[j0] == 0);
        int      i;
        double   minv = 0.0;
        int      fj   = -1;
        int      Lns  = 0;
        unsigned rem  = 0xFFu;
        unsigned pend = 0u;
        bool     first = true;

        const double uc = u_[cur];
        const float4 gc = tgt_[cur];

        if (fast) {
            // analytic iteration-1: pick j0 (cand=0 is the unique global min)
            i = row4col_[j0];
            fj = j0; Lns = 1;
            const bool mine = ((j0 & (AT - 1)) == tid);
            const int  slot = j0 >> 9;
            if (mine) {
                rem  &= ~(1u << slot);
                pend |=  (1u << slot);
                path_[j0] = (unsigned char)cur;
                #define SETJ0(n, on, shn, vvn, rcn) if (slot == n) shn = 0.0;
                FORALL(SETJ0)
                #undef SETJ0
            }
            if (tid == 0) { sc_i[0] = (short)i; sc_v[0] = 0.0; }
        } else {
            i = cur;
        }

        while (true) {
            if (tid == 0) redk_[s3 == 2 ? 0 : s3 + 1] = ~0ull;   // reset NEXT slot
            const double ui = u_[i];
            const float4 g  = tgt_[i];

            double bv = (double)INFINITY;
            int    bn = 0;

            if (first && fast) {
                // fused iterations 1+2: s = min(cand_cur, cand_win);
                // path = winner only on strict <
                #define FSTEP(n, on, shn, vvn, rcn)                             \
                {   double cand_c = ((0.0 + (double)COSTN(gc, on)) - uc) - vvn; \
                    double cand_w = ((0.0 + (double)COSTN(g,  on)) - ui) - vvn; \
                    bool wless = cand_w < cand_c;                               \
                    double s = wless ? cand_w : cand_c;                         \
                    if ((rem >> n) & 1u) {                                      \
                        shn = s;                                                \
                        path_[tid + AT * n] = (unsigned char)(wless ? i : cur); \
                        if (s < bv) { bv = s; bn = n; }                         \
                    }                                                           \
                }
                FORALL(FSTEP)
                #undef FSTEP
            } else if (first) {
                // plain reference iteration-1 scan from cur
                #define ISTEP(n, on, shn, vvn, rcn)                             \
                {   double s = ((0.0 + (double)COSTN(gc, on)) - uc) - vvn;      \
                    shn = s;                                                    \
                    path_[tid + AT * n] = (unsigned char)cur;                   \
                    if (s < bv) { bv = s; bn = n; }                             \
                }
                FORALL(ISTEP)
                #undef ISTEP
            } else {
                // min-update scan from row i — pure register arithmetic
                #define USTEP(n, on, shn, vvn, rcn)                             \
                {   double cand = ((minv + (double)COSTN(g, on)) - ui) - vvn;   \
                    bool valid = (rem >> n) & 1u;                               \
                    if (valid && cand < shn) {                                  \
                        shn = cand;                                             \
                        path_[tid + AT * n] = (unsigned char)i;                 \
                    }                                                           \
                    if (valid && shn < bv) { bv = shn; bn = n; }                \
                }
                FORALL(USTEP)
                #undef USTEP
            }
            first = false;

            // packed key: cand f64 bits (low 20 zero) | (row4col+1)<<12 | col
            int bi = tid + (bn << 9);
            int brc = -1;
            #define SELR(n, on, shn, vvn, rcn) if (bn == n) brc = rcn;
            FORALL(SELR)
            #undef SELR
            u64 key = (__double_as_longlong(bv) & ~0xFFFFFull)
                    | ((u64)(unsigned)(brc + 1) << 12) | (unsigned)bi;
            #pragma unroll
            for (int off = 32; off > 0; off >>= 1) {
                u64 ok = __shfl_down(key, off);
                if (ok < key) key = ok;
            }
            if ((tid & 63) == 0) atomicMin(&redk_[s3], key);
            __syncthreads();

            u64 fkey = redk_[s3];
            s3 = (s3 == 2) ? 0 : s3 + 1;

            fj    = (int)(fkey & 0xFFFull);
            int r = (int)((fkey >> 12) & 0xFFull) - 1;
            minv  = __longlong_as_double((long long)(fkey & ~0xFFFFFull));  // exact

            if ((fj & (AT - 1)) == tid) {
                rem &= ~(1u << (fj >> 9));
                if (r >= 0) pend |= (1u << (fj >> 9));
            }
            if (r < 0) break;                 // sink found
            if (tid == 0) { sc_i[Lns] = (short)r; sc_v[Lns] = minv; }
            Lns++;
            i = r;
        }

        // ---- row end: duals + augment ----
        const double dfin = minv;
        // owner v-patch in registers (sink term exactly 0, excluded from pend)
        #define VPAT(n, on, shn, vvn, rcn)                                      \
        if (pend & (1u << n)) {                                                 \
            vvn -= dfin - shn;                                                  \
            vtouch_[tid + AT * n] = 1;                                          \
        }
        FORALL(VPAT)
        #undef VPAT
        if (tid == 0) {
            u_[cur] += dfin;
            for (int e = 0; e < Lns; ++e)
                u_[sc_i[e]] += dfin - sc_v[e];   // pre-augment matched row of pick e
            int j = fj;
            while (true) {
                int i2 = path_[j];
                row4col_[j] = (short)i2;
                int nj = col4row_[i2];
                col4row_[i2] = (short)j;
                j = nj;
                if (i2 == cur) break;
            }
        }
        __syncthreads();   // publish row4col_/col4row_/u_ before next row
        FORALL(RELOAD)     // refresh row4col register copies
    }
#undef RELOAD
#undef COSTN
#undef FORALL

    // outputs (transposed case): order = argsort(col4row);
    // row_ind = col4row[order]; col_ind = order.
    if (tid < NTGT) {
        int val = col4row_[tid];
        int rank = 0;
        #pragma unroll
        for (int k = 0; k < NTGT; ++k) rank += (col4row_[k] < val);
        row_out[b * NTGT + rank] = (float)val;
        col_out[b * NTGT + rank] = (float)tid;
    }
}

extern "C" void kernel_launch(void* const* d_in, const int* in_sizes, int n_in,
                              void* d_out, int out_size, void* d_ws, size_t ws_size,
                              hipStream_t stream) {
    const float* outputs = (const float*)d_in[0];   // [16, 4096, 4]
    const float* targets = (const float*)d_in[1];   // [16, 128, 4]
    float* out = (float*)d_out;                     // C | row_ind | col_ind (as f32)

    u64* rowkey2 = (u64*)d_ws;                      // NB*NSLOT*NTGT*8 = 1 MB

    hipLaunchKernelGGL(rowmin_kernel, dim3(NB * NSLOT), dim3(256), 0, stream,
                       outputs, targets, rowkey2);
    hipLaunchKernelGGL(fused_kernel, dim3(NB + NCOST), dim3(AT), 0, stream,
                       outputs, targets, rowkey2, out,
                       out + CELEMS, out + CELEMS + NB * NTGT);
}

// Round 20
// 31.145 us; speedup vs baseline: 1.3866x; 1.0188x over previous
//
#include <hip/hip_runtime.h>
#include <math.h>

#define NB   16
#define NQ   4096
#define NTGT 128
#define CELEMS (NB * NQ * NTGT)

#define NSLOT 64           // rowmin slots per batch
#define AT   512           // block size (both roles) — 8 waves for latency hiding
#define ACPT 8             // cols per lsa thread (NQ / AT)
#define ANW  (AT / 64)     // 8 waves
#define NCOST (CELEMS / 4 / 2048)   // 1024 C-writer blocks (4 float4/thread)

typedef unsigned long long u64;

// ---------------- kernel 1: per-row (target) min/argmin only -----------------
__global__ __launch_bounds__(256) void rowmin_kernel(
    const float* __restrict__ outputs,
    const float* __restrict__ targets,
    u64*   __restrict__ rowkey2)      // [NB][NSLOT][NTGT]
{
    __shared__ u64 part[4][NTGT];     // 4 KB
    const int tid  = threadIdx.x;
    const int t4   = tid & 31;
    const int b    = blockIdx.x >> 6;            // 64 blocks per batch
    const int blk  = blockIdx.x & (NSLOT - 1);
    const int idx0 = blockIdx.x * 2048 + tid;

    const float4* tg = reinterpret_cast<const float4*>(targets) + (b << 7) + (t4 << 2);
    float4 g[4];
    #pragma unroll
    for (int f = 0; f < 4; ++f) g[f] = tg[f];

    u64 keymin[4] = {~0ull, ~0ull, ~0ull, ~0ull};

    #pragma unroll
    for (int e = 0; e < 8; ++e) {
        int idx = idx0 + 256 * e;
        int bq  = idx >> 5;
        float4 o = reinterpret_cast<const float4*>(outputs)[bq];
        u64 q = (u64)(unsigned)(bq & (NQ - 1));
        #pragma unroll
        for (int f = 0; f < 4; ++f) {
            float4 gg = g[f];
            float r = (fabsf(o.x - gg.x) + fabsf(o.y - gg.y)) +
                      (fabsf(o.z - gg.z) + fabsf(o.w - gg.w));
            u64 key = (((u64)__float_as_uint(r)) << 32) | q;
            if (key < keymin[f]) keymin[f] = key;
        }
    }

    #pragma unroll
    for (int f = 0; f < 4; ++f) {
        u64 ov = __shfl_xor(keymin[f], 32);
        if (ov < keymin[f]) keymin[f] = ov;
    }
    if ((tid & 63) < 32) {
        int w = tid >> 6;
        #pragma unroll
        for (int f = 0; f < 4; ++f) part[w][(t4 << 2) + f] = keymin[f];
    }
    __syncthreads();

    if (tid < NTGT) {
        u64 k = part[0][tid];
        #pragma unroll
        for (int s = 1; s < 4; ++s) { u64 ov = part[s][tid]; if (ov < k) k = ov; }
        rowkey2[(((size_t)b * NSLOT) + blk) * NTGT + tid] = k;
    }
}

// ---------------- kernel 2: fused {lsa blocks 0..15} + {C-writer blocks} -----
// lsa: exact f64 Jonker-Volgenant -> provably optimal matching == scipy
// (unique optimum; all arithmetic exact: multiples of 2^-24 << 2^53).
// Per-thread 8-column state in NAMED registers. Argmin reduce: packed u64
// (cand f64 bits, low 12 mantissa bits carry the column; values are
// multiples of 2^-24 < 16 so low 12 bits are zero -> lossless, and col-in-
// low-bits preserves lowest-index tie-break). One barrier per iteration.
__global__ __launch_bounds__(AT, 1) void fused_kernel(
    const float* __restrict__ outputs,
    const float* __restrict__ targets,
    const u64*   __restrict__ rowkey2,
    float* __restrict__ C,
    float* __restrict__ row_out,   // [NB, NTGT] as float
    float* __restrict__ col_out)   // [NB, NTGT] as float
{
    __shared__ unsigned claim_[NQ];         // 16 KB
    __shared__ short  row4col_[NQ];         // 8 KB
    __shared__ unsigned char path_[NQ];     // 4 KB
    __shared__ unsigned char vtouch_[NQ];   // 4 KB
    __shared__ float4 tgt_[NTGT];           // 2 KB
    __shared__ double u_[NTGT];             // 1 KB
    __shared__ u64    red2_[4][NTGT];       // 4 KB
    __shared__ int    rowarg_[NTGT];
    __shared__ short  col4row_[NTGT];
    __shared__ short  left_[NTGT];
    __shared__ short  sc_i[NTGT];
    __shared__ double sc_v[NTGT];
    __shared__ u64    redk_[2][ANW];
    __shared__ u64    bmask_[2];

    const int tid = threadIdx.x;

    if (blockIdx.x >= NB) {
        // ---------------- C-writer role: pure streaming ----------------
        const int blk = blockIdx.x - NB;
        const int t4  = tid & 31;
        const float4* tg = reinterpret_cast<const float4*>(targets);
        float4 g0, g1, g2, g3;
        {
            int b = (blk * 2048 + tid) >> 17;
            const float4* tgb = tg + (b << 7) + (t4 << 2);
            g0 = tgb[0]; g1 = tgb[1]; g2 = tgb[2]; g3 = tgb[3];
        }
        #pragma unroll
        for (int e = 0; e < 4; ++e) {
            int f  = blk * 2048 + e * 512 + tid;   // float4 index into C
            int bq = f >> 5;
            float4 o = reinterpret_cast<const float4*>(outputs)[bq];
            float4 r;
            r.x = (fabsf(o.x - g0.x) + fabsf(o.y - g0.y)) + (fabsf(o.z - g0.z) + fabsf(o.w - g0.w));
            r.y = (fabsf(o.x - g1.x) + fabsf(o.y - g1.y)) + (fabsf(o.z - g1.z) + fabsf(o.w - g1.w));
            r.z = (fabsf(o.x - g2.x) + fabsf(o.y - g2.y)) + (fabsf(o.z - g2.z) + fabsf(o.w - g2.w));
            r.w = (fabsf(o.x - g3.x) + fabsf(o.y - g3.y)) + (fabsf(o.z - g3.z) + fabsf(o.w - g3.w));
            reinterpret_cast<float4*>(C)[f] = r;
        }
        return;
    }

    // ---------------- lsa role: one block per batch ----------------
    const int b = blockIdx.x;
    const float4* outq = reinterpret_cast<const float4*>(outputs) + b * NQ;

#define FORALL(M) \
    M(0,oo0,sh0,vv0) M(1,oo1,sh1,vv1) M(2,oo2,sh2,vv2) M(3,oo3,sh3,vv3) \
    M(4,oo4,sh4,vv4) M(5,oo5,sh5,vv5) M(6,oo6,sh6,vv6) M(7,oo7,sh7,vv7)

    // named per-column registers (static indexing only)
#define DECL(n, on, shn, vvn) \
    float4 on = outq[tid + AT * n]; double shn = 0.0, vvn = 0.0;
    FORALL(DECL)
#undef DECL

    #pragma unroll
    for (int kk = 0; kk < ACPT; ++kk) {
        int k = tid + AT * kk;
        row4col_[k] = -1;
        claim_[k] = 0xFFFFFFFFu;
        vtouch_[k] = 0;
    }

    // reduce the 64 rowkey slots per row (coalesced)
    {
        const int t = tid & 127, s = tid >> 7;            // 4 slices x 16 slots
        const u64* rk = rowkey2 + (size_t)b * NSLOT * NTGT;
        u64 k = ~0ull;
        #pragma unroll
        for (int gg = 0; gg < NSLOT / 4; ++gg) {
            u64 ov = rk[(s * (NSLOT / 4) + gg) * NTGT + t];
            if (ov < k) k = ov;
        }
        red2_[s][t] = k;
    }
    __syncthreads();

    if (tid < NTGT) {
        u64 key = red2_[0][tid];
        #pragma unroll
        for (int s = 1; s < 4; ++s) { u64 ov = red2_[s][tid]; if (ov < key) key = ov; }
        u_[tid] = (double)__uint_as_float((unsigned)(key >> 32));
        rowarg_[tid] = (int)(key & 0xffffffffu);
        tgt_[tid] = reinterpret_cast<const float4*>(targets)[b * NTGT + tid];
    }
    __syncthreads();

    // greedy claim of tight edges: lowest row wins each contested column
    if (tid < NTGT) atomicMin(&claim_[rowarg_[tid]], (unsigned)tid);
    __syncthreads();

    bool un = false;
    if (tid < NTGT) {
        int j = rowarg_[tid];
        bool won = (claim_[j] == (unsigned)tid);
        col4row_[tid] = won ? (short)j : (short)-1;
        if (won) row4col_[j] = (short)tid;
        un = !won;
    }
    {
        u64 m = __ballot(un);
        if ((tid & 63) == 0 && (tid >> 6) < 2) bmask_[tid >> 6] = m;
    }
    __syncthreads();
    const int nleft = __popcll(bmask_[0]) + __popcll(bmask_[1]);
    if (un) {
        int lane = tid & 63, w = tid >> 6;
        int r = __popcll(bmask_[w] & ((1ull << lane) - 1)) + (w ? __popcll(bmask_[0]) : 0);
        left_[r] = (short)tid;
    }
    __syncthreads();

    int parity = 0;

#define COSTN(g, on) ((fabsf((on).x - (g).x) + fabsf((on).y - (g).y)) + \
                      (fabsf((on).z - (g).z) + fabsf((on).w - (g).w)))

    for (int li = 0; li < nleft; ++li) {
        const int cur = left_[li];
        const int j0  = rowarg_[cur];
        const bool fast = (vtouch_[j0] == 0);
        int      i;
        double   minv = 0.0;
        int      fj   = -1;
        int      Lns  = 0;
        unsigned rem  = 0xFFu;
        unsigned pend = 0u;
        bool     first = true;

        const double uc = u_[cur];
        const float4 gc = tgt_[cur];

        if (fast) {
            // analytic iteration-1: pick j0 (cand=0 is the unique global min)
            i = row4col_[j0];
            fj = j0; Lns = 1;
            const bool mine = ((j0 & (AT - 1)) == tid);
            const int  slot = j0 >> 9;
            if (mine) {
                rem  &= ~(1u << slot);
                pend |=  (1u << slot);
                path_[j0] = (unsigned char)cur;
                #define SETJ0(n, on, shn, vvn) if (slot == n) shn = 0.0;
                FORALL(SETJ0)
                #undef SETJ0
            }
            if (tid == 0) { sc_i[0] = (short)i; sc_v[0] = 0.0; }
        } else {
            i = cur;
        }

        while (true) {
            const double ui = u_[i];
            const float4 g  = tgt_[i];

            double bv = (double)INFINITY;
            int    bn = 0;

            if (first && fast) {
                // fused iterations 1+2: s = min(cand_cur, cand_win);
                // path = winner only on strict <
                #define FSTEP(n, on, shn, vvn)                                  \
                {   double cand_c = ((0.0 + (double)COSTN(gc, on)) - uc) - vvn; \
                    double cand_w = ((0.0 + (double)COSTN(g,  on)) - ui) - vvn; \
                    bool wless = cand_w < cand_c;                               \
                    double s = wless ? cand_w : cand_c;                         \
                    if ((rem >> n) & 1u) {                                      \
                        shn = s;                                                \
                        path_[tid + AT * n] = (unsigned char)(wless ? i : cur); \
                        if (s < bv) { bv = s; bn = n; }                         \
                    }                                                           \
                }
                FORALL(FSTEP)
                #undef FSTEP
            } else if (first) {
                // plain reference iteration-1 scan from cur
                #define ISTEP(n, on, shn, vvn)                                  \
                {   double s = ((0.0 + (double)COSTN(gc, on)) - uc) - vvn;      \
                    shn = s;                                                    \
                    path_[tid + AT * n] = (unsigned char)cur;                   \
                    if (s < bv) { bv = s; bn = n; }                             \
                }
                FORALL(ISTEP)
                #undef ISTEP
            } else {
                // min-update scan from row i — pure register arithmetic
                #define USTEP(n, on, shn, vvn)                                  \
                {   double cand = ((minv + (double)COSTN(g, on)) - ui) - vvn;   \
                    bool valid = (rem >> n) & 1u;                               \
                    if (valid && cand < shn) {                                  \
                        shn = cand;                                             \
                        path_[tid + AT * n] = (unsigned char)i;                 \
                    }                                                           \
                    if (valid && shn < bv) { bv = shn; bn = n; }                \
                }
                FORALL(USTEP)
                #undef USTEP
            }
            first = false;

            // lossless packed u64 argmin reduce: (f64 bits & ~0xFFF) | col
            int bi = tid + (bn << 9);
            u64 key = (__double_as_longlong(bv) & ~0xFFFull) | (unsigned)bi;
            #pragma unroll
            for (int off = 32; off > 0; off >>= 1) {
                u64 ok = __shfl_down(key, off);
                if (ok < key) key = ok;
            }
            if ((tid & 63) == 0) redk_[parity][tid >> 6] = key;
            __syncthreads();

            u64 fkey = redk_[parity][0];
            #pragma unroll
            for (int w = 1; w < ANW; ++w) {
                u64 ok = redk_[parity][w];
                if (ok < fkey) fkey = ok;
            }
            parity ^= 1;

            fj   = (int)(fkey & 0xFFFull);
            minv = __longlong_as_double((long long)(fkey & ~0xFFFull));  // exact

            int r = row4col_[fj];
            if ((fj & (AT - 1)) == tid) {
                rem &= ~(1u << (fj >> 9));
                if (r >= 0) pend |= (1u << (fj >> 9));
            }
            if (r < 0) break;                 // sink found
            if (tid == 0) { sc_i[Lns] = (short)r; sc_v[Lns] = minv; }
            Lns++;
            i = r;
        }

        // ---- row end: duals + augment ----
        const double dfin = minv;
        // owner v-patch in registers (sink term exactly 0, excluded from pend)
        #define VPAT(n, on, shn, vvn)                                           \
        if (pend & (1u << n)) {                                                 \
            vvn -= dfin - shn;                                                  \
            vtouch_[tid + AT * n] = 1;                                          \
        }
        FORALL(VPAT)
        #undef VPAT
        if (tid == 0) {
            u_[cur] += dfin;
            for (int e = 0; e < Lns; ++e)
                u_[sc_i[e]] += dfin - sc_v[e];   // pre-augment matched row of pick e
            int j = fj;
            while (true) {
                int i2 = path_[j];
                row4col_[j] = (short)i2;
                int nj = col4row_[i2];
                col4row_[i2] = (short)j;
                j = nj;
                if (i2 == cur) break;
            }
        }
        __syncthreads();   // publish row4col_/col4row_/u_ before next row
    }
#undef COSTN
#undef FORALL

    // outputs (transposed case): order = argsort(col4row);
    // row_ind = col4row[order]; col_ind = order.
    if (tid < NTGT) {
        int val = col4row_[tid];
        int rank = 0;
        #pragma unroll
        for (int k = 0; k < NTGT; ++k) rank += (col4row_[k] < val);
        row_out[b * NTGT + rank] = (float)val;
        col_out[b * NTGT + rank] = (float)tid;
    }
}

extern "C" void kernel_launch(void* const* d_in, const int* in_sizes, int n_in,
                              void* d_out, int out_size, void* d_ws, size_t ws_size,
                              hipStream_t stream) {
    const float* outputs = (const float*)d_in[0];   // [16, 4096, 4]
    const float* targets = (const float*)d_in[1];   // [16, 128, 4]
    float* out = (float*)d_out;                     // C | row_ind | col_ind (as f32)

    u64* rowkey2 = (u64*)d_ws;                      // NB*NSLOT*NTGT*8 = 1 MB

    hipLaunchKernelGGL(rowmin_kernel, dim3(NB * NSLOT), dim3(256), 0, stream,
                       outputs, targets, rowkey2);
    hipLaunchKernelGGL(fused_kernel, dim3(NB + NCOST), dim3(AT), 0, stream,
                       outputs, targets, rowkey2, out,
                       out + CELEMS, out + CELEMS + NB * NTGT);
}